// Round 3
// baseline (451.286 us; speedup 1.0000x reference)
//
#include <hip/hip_runtime.h>
#include <stdint.h>

typedef int int32x4  __attribute__((ext_vector_type(4)));
typedef int int32x16 __attribute__((ext_vector_type(16)));

#define IN_F   4096
#define OUT_F  4096
#define ROWS   8192   /* 4 * 2048 */

#define BM 256
#define BN 256
#define BK 64
#define NT (IN_F / BK)           /* 64 K-tiles */
#define TILE_LDS 32768           /* A 16KB + B 16KB per tile */
#define LDS_TOTAL (4 * TILE_LDS) /* quad buffer = 128 KB (dynamic) */

// async global->LDS, 16B per lane; LDS dest must be lane-contiguous (m104/m108)
#define GLOAD_LDS16(g, l)                                                      \
  __builtin_amdgcn_global_load_lds(                                            \
      (const __attribute__((address_space(1))) void*)(g),                      \
      (__attribute__((address_space(3))) void*)(l), 16, 0, 0)

// tile gate (T4): counted vmcnt (own 4 oldest loads = tile t landed), then
// barrier (=> ALL waves' tile-t loads landed, and all waves are past their
// last ds_read of buf[t-1], so its DMA overwrite is safe).
#define GATE(N)                                                                \
  do {                                                                         \
    asm volatile("s_waitcnt vmcnt(" #N ")" ::: "memory");                      \
    __builtin_amdgcn_sched_barrier(0);                                         \
    __builtin_amdgcn_s_barrier();                                              \
    __builtin_amdgcn_sched_barrier(0);                                         \
  } while (0)

__device__ __forceinline__ int pack4i(int a, int b, int c, int d) {
  return (a & 0xff) | ((b & 0xff) << 8) | ((c & 0xff) << 16) | (d << 24);
}

// ---- fused conversion: x int32->int8 and w fp32->int8, grid-stride ---------
#define CVT_BLOCKS 2048
#define CVT_NX 8388608   /* 8192*4096/4 int4 chunks */
#define CVT_NT 12582912  /* + 4096*4096/4 float4 chunks */
__global__ void __launch_bounds__(256) cvt_kernel(const int4* __restrict__ x,
                                                  const float4* __restrict__ w,
                                                  int* __restrict__ ox,
                                                  int* __restrict__ ow) {
  size_t i = (size_t)blockIdx.x * 256 + threadIdx.x;
  for (; i < CVT_NT; i += (size_t)CVT_BLOCKS * 256) {
    if (i < CVT_NX) {            // wave-uniform: CVT_NX % 256 == 0
      int4 a = x[i];
      ox[i] = pack4i(a.x, a.y, a.z, a.w);
    } else {
      size_t j = i - CVT_NX;
      float4 a = w[j];
      ow[j] = pack4i(__float2int_rn(a.x), __float2int_rn(a.y),
                     __float2int_rn(a.z), __float2int_rn(a.w));
    }
  }
}

// ---- i8 MFMA GEMM: C[m,n] = sum_k A[m,k]*B[n,k] (row-major [rows][K]) ------
// 256x256 block, BK=64, 8 waves (2x4), per-wave 128x64 via 4x2 of
// mfma_i32_32x32x32_i8.  Quad-buffered LDS, prefetch depth 3.
//
// K-OUTER LDS LAYOUT (conflict fix): tile stored as 16B units at
// phys = c*256 + r  (c = 16B k-chunk 0..3, r = row 0..255).  A wave's
// fragment read (fixed c per hi-half, 32 consecutive rows) is a contiguous
// 512B burst per half-wave -> stride-1 LDS pattern, ~0 bank conflicts
// (m134), vs the previous row-major layout's measured 4.0 extra cyc/read.
// Staging keeps LDS lane-linear (thread t -> unit t of round j): thread t
// stages logical (r = t&255, c = 2j + (t>>8)); phys = (2j+(t>>8))*256 +
// (t&255) = j*512 + t  -> dest = base + j*8192 + t*16.  Global source is
// row-strided 16B/lane; the 4 chunks of each row land on the same L2 line
// within one tile, so HBM fetch efficiency is preserved.
//
// PHASE DISCIPLINE (m201/T3): per K-tile, 2 phases of {6 ds_read, 2
// global_load_lds, s_barrier, lgkmcnt(0), setprio(1), 8 MFMA, setprio(0)};
// counted vmcnt(8) gate once per tile, never drained in the main loop.
//
// Fragment lane maps (inherited, harness-verified): A/B: m|n = lane&31,
// k = (lane>>5)*16 + j (lane's 16B).  C/D: col = lane&31,
// row = (reg&3) + 8*(reg>>2) + 4*(lane>>5).
__global__ void __launch_bounds__(512) gemm_i8_kernel(
    const int8_t* __restrict__ A8, const int8_t* __restrict__ B8,
    const float* __restrict__ bias, const float* __restrict__ alpha_p,
    int* __restrict__ out) {
  extern __shared__ int8_t lds[];

  const int t    = threadIdx.x;
  const int wave = t >> 6;
  const int lane = t & 63;
  const int l31  = lane & 31;
  const int hi   = lane >> 5;   // 0..1
  const int wm   = wave >> 2;   // 0..1  (M rows of waves)
  const int wn   = wave & 3;    // 0..3  (N cols of waves)

  // XCD-aware bijective swizzle (T1): 512 blocks % 8 == 0.
  const int flat = blockIdx.y * gridDim.x + blockIdx.x;  // 0..511
  const int wid  = (flat & 7) * 64 + (flat >> 3);
  const int bm   = wid >> 4;    // 0..31
  const int bn   = wid & 15;    // 0..15

  // staging source (K-outer map): r = t&255, base k-chunk = t>>8
  const int rS = t & 255;
  const int cS = (t >> 8) * 16;
  const int8_t* gA = A8 + (size_t)(bm * BM + rS) * IN_F + cS;
  const int8_t* gB = B8 + (size_t)(bn * BN + rS) * IN_F + cS;
  const int ldst = t * 16;

  const int aoff = wm * 128 + l31;  // row offset of this lane's A fragments
  const int boff = wn * 64  + l31;  // row offset of this lane's B fragments

  int32x16 acc[4][2] = {};

  auto issueA = [&](int tile) {
    int8_t* base = lds + (tile & 3) * TILE_LDS;
    const int k0 = tile * BK;
    GLOAD_LDS16(gA + k0,      base + ldst);          // round j=0: c = t>>8
    GLOAD_LDS16(gA + k0 + 32, base + 8192 + ldst);   // round j=1: c = 2+(t>>8)
  };
  auto issueB = [&](int tile) {
    int8_t* base = lds + (tile & 3) * TILE_LDS + 16384;
    const int k0 = tile * BK;
    GLOAD_LDS16(gB + k0,      base + ldst);
    GLOAD_LDS16(gB + k0 + 32, base + 8192 + ldst);
  };

  // one phase: 6 ds_read + (optional) 2 DMA issues + barrier + lgkm(0) + 8 MFMA
  auto phase = [&](int tile, int ks, int itile, int mode) {
    const int32x4* As4 = (const int32x4*)(lds + (tile & 3) * TILE_LDS);
    const int32x4* Bs4 = As4 + 1024;                 // +16 KB
    const int kb = (ks * 2 + hi) * 256;              // k-chunk plane
    int32x4 af[4], bf[2];
#pragma unroll
    for (int mi = 0; mi < 4; ++mi) af[mi] = As4[kb + aoff + mi * 32];
#pragma unroll
    for (int ni = 0; ni < 2; ++ni) bf[ni] = Bs4[kb + boff + ni * 32];
    if (mode == 0) issueA(itile);
    else if (mode == 1) issueB(itile);
    __builtin_amdgcn_s_barrier();
    asm volatile("s_waitcnt lgkmcnt(0)" ::: "memory");
    __builtin_amdgcn_sched_barrier(0);               // rule 18
    __builtin_amdgcn_s_setprio(1);                   // T5: phase role-split
#pragma unroll
    for (int mi = 0; mi < 4; ++mi)
#pragma unroll
      for (int ni = 0; ni < 2; ++ni)
        acc[mi][ni] = __builtin_amdgcn_mfma_i32_32x32x32_i8(
            af[mi], bf[ni], acc[mi][ni], 0, 0, 0);
    __builtin_amdgcn_s_setprio(0);
  };

  // prologue: tiles 0..2 in flight (12 loads/wave, issue order A0 A1 B0 B1)
  issueA(0); issueB(0);
  issueA(1); issueB(1);
  issueA(2); issueB(2);

  for (int tt = 0; tt < NT - 3; ++tt) {
    GATE(8);                       // tile tt landed everywhere; buf[tt-1] free
    phase(tt, 0, tt + 3, 0);       // ks0 + issue A(tt+3) -> outstanding 10
    phase(tt, 1, tt + 3, 1);       // ks1 + issue B(tt+3) -> outstanding 12
  }
  // epilogue peel: drain 8 -> 4 -> 0 (literal immediates)
  GATE(8); phase(NT - 3, 0, 0, 2); phase(NT - 3, 1, 0, 2);
  GATE(4); phase(NT - 2, 0, 0, 2); phase(NT - 2, 1, 0, 2);
  GATE(0); phase(NT - 1, 0, 0, 2); phase(NT - 1, 1, 0, 2);

  // epilogue: C/D col = lane&31, row = (reg&3) + 8*(reg>>2) + 4*hi
  const float alpha = *alpha_p;
#pragma unroll
  for (int mi = 0; mi < 4; ++mi) {
    const int rowt = bm * BM + wm * 128 + mi * 32 + hi * 4;
#pragma unroll
    for (int ni = 0; ni < 2; ++ni) {
      const int col = bn * BN + wn * 64 + ni * 32 + l31;
      const float bv = bias[col];
#pragma unroll
      for (int r = 0; r < 16; ++r) {
        const int row = rowt + (r & 3) + 8 * (r >> 2);
        float v = rintf((float)acc[mi][ni][r] * alpha + bv);
        v = fminf(fmaxf(v, -128.f), 127.f);
        out[(size_t)row * OUT_F + col] = (int)v;
      }
    }
  }
}

extern "C" void kernel_launch(void* const* d_in, const int* in_sizes, int n_in,
                              void* d_out, int out_size, void* d_ws, size_t ws_size,
                              hipStream_t stream) {
  const int*   x     = (const int*)d_in[0];    // [8192, 4096] int8-valued
  const float* w     = (const float*)d_in[1];  // [4096, 4096] int8-valued
  const float* bias  = (const float*)d_in[2];  // [4096]
  const float* alpha = (const float*)d_in[3];  // scalar
  int* out = (int*)d_out;                      // [8192, 4096] int32 (int8 values)

  int8_t* x8 = (int8_t*)d_ws;                        // 33,554,432 B
  int8_t* w8 = x8 + (size_t)ROWS * IN_F;             // 16,777,216 B (total 48 MB)

  static bool attr_done = false;
  if (!attr_done) {
    (void)hipFuncSetAttribute(reinterpret_cast<const void*>(gemm_i8_kernel),
                              hipFuncAttributeMaxDynamicSharedMemorySize,
                              LDS_TOTAL);
    attr_done = true;
  }

  cvt_kernel<<<CVT_BLOCKS, 256, 0, stream>>>((const int4*)x, (const float4*)w,
                                             (int*)x8, (int*)w8);

  dim3 grid(OUT_F / BN, ROWS / BM);  // (16, 32) = 512 blocks, 2 clean rounds
  gemm_i8_kernel<<<grid, 512, LDS_TOTAL, stream>>>(x8, w8, bias, alpha, out);
}